// Round 1
// 1402.266 us; speedup vs baseline: 1.1695x; 1.1695x over previous
//
#include <hip/hip_runtime.h>

// convPbc as implicit GEMM, round 3: software-pipelined main loop.
//   Pre-pass 1: helically-padded x as bf16, channel stride 1232 (16B-aligned rows),
//               vectorized short8 stores.
//   Pre-pass 2: W -> bf16 (512x4096), vectorized.
//   Main: C[M][N] = A * W^T via mfma_f32_16x16x32_bf16, 128x128 tile, 4 waves 64x64.
//     NEW: B LDS double-buffered (2x8KB) with DMA issued ONE K-STEP AHEAD; A register
//     fragments double-buffered (afA/afB, loop unrolled x2 for static indexing).
//     One __syncthreads per k-step (was 2 + full same-iteration vmcnt drain) -> the
//     drain now waits on loads that had a whole compute phase to land.

#define BM 128
#define BN 128

typedef __attribute__((ext_vector_type(8))) short short8;
typedef __attribute__((ext_vector_type(4))) float f32x4;

struct __attribute__((packed)) u16x4 { unsigned short a, b, c, d; };  // 8B, 2B-align

__device__ __forceinline__ unsigned short f2bf(float f) {
    union { float f; unsigned u; } v; v.f = f;
    unsigned r = v.u + 0x7FFF + ((v.u >> 16) & 1);  // RNE
    return (unsigned short)(r >> 16);
}

__device__ __forceinline__ void async_b128(const void* g, void* l) {
    __builtin_amdgcn_global_load_lds(
        (const __attribute__((address_space(1))) void*)g,
        (__attribute__((address_space(3))) void*)l, 16, 0, 0);
}

// ---------------- pre-pass kernels ----------------
// vectorized: one block per (b,c); threads 0..153 write one 16B chunk of the
// 1232-u16 padded channel row.
__global__ __launch_bounds__(256) void build_pad_vec(const float* __restrict__ x,
                                                     unsigned short* __restrict__ xp) {
    const int bc = blockIdx.x;
    const int t  = threadIdx.x;
    if (t >= 154) return;
    const float* xb = x + (long)bc * 1024;
    union { unsigned short h[8]; short8 v; } u;
    if (t < 128) {                                   // pure copy region v<1024
        const float4 f0 = *(const float4*)(xb + t * 8);
        const float4 f1 = *(const float4*)(xb + t * 8 + 4);
        u.h[0] = f2bf(f0.x); u.h[1] = f2bf(f0.y); u.h[2] = f2bf(f0.z); u.h[3] = f2bf(f0.w);
        u.h[4] = f2bf(f1.x); u.h[5] = f2bf(f1.y); u.h[6] = f2bf(f1.z); u.h[7] = f2bf(f1.w);
    } else {                                         // pad region 1024..1231
        #pragma unroll
        for (int e = 0; e < 8; ++e) {
            const int v = t * 8 + e;
            const int p = (v * 7490) >> 18;          // exact v/35 for v<43690
            const int q = v - p * 35;
            float val = 0.0f;
            if (p >= 32 && q >= 32) val = xb[((p - 32) << 5) + (q - 32)];
            u.h[e] = f2bf(val);
        }
    }
    *(short8*)(xp + (long)bc * 1232 + t * 8) = u.v;
}

// scalar fallback (stride 1225), identical to round-2 version
__global__ __launch_bounds__(256) void build_pad_s(const float* __restrict__ x,
                                                   unsigned short* __restrict__ xp) {
    const int v = blockIdx.x * 256 + threadIdx.x;
    const int bc = blockIdx.y;
    if (v >= 1225) return;
    const int p = (v * 7490) >> 18;
    const int q = v - p * 35;
    const float* xb = x + (long)bc * 1024;
    float val = (v < 1024) ? xb[v] : 0.0f;
    if (p >= 32 && q >= 32) val += xb[((p - 32) << 5) + (q - 32)];
    xp[(long)bc * 1225 + v] = f2bf(val);
}

__global__ __launch_bounds__(256) void cvt_w(const float* __restrict__ W,
                                             unsigned short* __restrict__ Wb) {
    const int i = (blockIdx.x * 256 + threadIdx.x) * 8;   // 2M elems / 8
    const float4 f0 = *(const float4*)(W + i);
    const float4 f1 = *(const float4*)(W + i + 4);
    union { unsigned short h[8]; short8 v; } u;
    u.h[0] = f2bf(f0.x); u.h[1] = f2bf(f0.y); u.h[2] = f2bf(f0.z); u.h[3] = f2bf(f0.w);
    u.h[4] = f2bf(f1.x); u.h[5] = f2bf(f1.y); u.h[6] = f2bf(f1.z); u.h[7] = f2bf(f1.w);
    *(short8*)(Wb + i) = u.v;
}

// ---------------- main kernel (pipelined) ----------------
__global__ __launch_bounds__(256) void convpbc_mfma3(
    const unsigned short* __restrict__ xpad,  // (128,256,cstride) bf16
    const unsigned short* __restrict__ Wb,    // (512,4096) bf16
    const float* __restrict__ bias,
    float* __restrict__ y,
    const int cstride)
{
    __shared__ __attribute__((aligned(16))) unsigned short Blds[2 * BN * 32];  // 16 KB

    const int tid = threadIdx.x;
    const int bid = blockIdx.x;
    const int nt = bid & 3;
    const int mt = bid >> 2;
    const int batch = mt >> 3;
    const int s0 = (mt & 7) * BM;
    const int i0 = (mt & 7) * 4;

    const int lane = tid & 63;
    const int w    = tid >> 6;
    const int wm   = (w >> 1) * 64;
    const int wn   = (w & 1) * 64;
    const int lr   = lane & 15;
    const int quad = lane >> 4;

    // ---- A direct-load setup ----
    const int fi0 = (quad & 1) * 2;
    const unsigned short* ab = xpad + (long)(batch * 256 + (quad >> 1)) * cstride;
    int aoff[4];
    #pragma unroll
    for (int mi = 0; mi < 4; ++mi) {
        const int i_mi = i0 + (wm >> 5) + (mi >> 1) + fi0;
        const int j_mi = (mi & 1) * 16 + lr;
        aoff[mi] = i_mi * 35 + j_mi;
    }
    const int cs2 = 2 * cstride;   // one k-step = 2 channels
    const int cs4 = 4 * cstride;

    // ---- B staging setup ----
    const int brow0 = w * 32 + (lane >> 2);
    const int brow1 = brow0 + 16;
    const int bseg  = lane & 3;
    const unsigned short* bg0 =
        Wb + (long)(nt * BN + brow0) * 4096 + (bseg ^ ((brow0 >> 1) & 3)) * 8;
    const unsigned short* bg1 =
        Wb + (long)(nt * BN + brow1) * 4096 + (bseg ^ ((brow1 >> 1) & 3)) * 8;
    unsigned short* const bl0_0 = &Blds[(w * 32) * 32];   // wave-uniform bases, buf0
    unsigned short* const bl1_0 = bl0_0 + 512;
    unsigned short* const bl0_1 = bl0_0 + 4096;           // buf1
    unsigned short* const bl1_1 = bl0_0 + 4608;

    int bfaddr[4];
    #pragma unroll
    for (int ni = 0; ni < 4; ++ni) {
        const int row = wn + ni * 16 + lr;
        bfaddr[ni] = row * 32 + (quad ^ ((row >> 1) & 3)) * 8;
    }

    f32x4 acc[4][4] = {};
    short8 afA[4], afB[4];

    #define LOAD_A(dst, base)                                                    \
        _Pragma("unroll")                                                        \
        for (int mi = 0; mi < 4; ++mi) {                                         \
            union { unsigned short h[8]; short8 f; } u_;                         \
            *(u16x4*)&u_.h[0] = *(const u16x4*)((base) + aoff[mi]);              \
            *(u16x4*)&u_.h[4] = *(const u16x4*)((base) + aoff[mi] + 35);         \
            dst[mi] = u_.f;                                                      \
        }

    // prologue: stage k-step 0 (buf0, afA)
    async_b128(bg0, bl0_0);
    async_b128(bg1, bl1_0);
    LOAD_A(afA, ab)

    const unsigned short* abs_ = ab;     // channel base of current EVEN step

    for (int k0 = 0; k0 < 4096; k0 += 64) {
        // ================= EVEN step (buf0, afA) =================
        __syncthreads();   // drains vmcnt: this step's DMA + A regs are resident

        // prefetch odd step -> buf1, afB
        async_b128(bg0 + k0 + 32, bl0_1);
        async_b128(bg1 + k0 + 32, bl1_1);
        LOAD_A(afB, abs_ + cs2)

        {
            short8 bf[4];
            #pragma unroll
            for (int ni = 0; ni < 4; ++ni)
                bf[ni] = *(const short8*)&Blds[bfaddr[ni]];
            #pragma unroll
            for (int mi = 0; mi < 4; ++mi)
                #pragma unroll
                for (int ni = 0; ni < 4; ++ni)
                    acc[mi][ni] = __builtin_amdgcn_mfma_f32_16x16x32_bf16(
                        afA[mi], bf[ni], acc[mi][ni], 0, 0, 0);
        }

        // ================= ODD step (buf1, afB) =================
        __syncthreads();   // odd DMA + afB resident; buf0 reads all retired

        if (k0 + 64 < 4096) {           // prefetch next even step -> buf0, afA
            async_b128(bg0 + k0 + 64, bl0_0);
            async_b128(bg1 + k0 + 64, bl1_0);
            LOAD_A(afA, abs_ + cs4)
        }

        {
            short8 bf[4];
            #pragma unroll
            for (int ni = 0; ni < 4; ++ni)
                bf[ni] = *(const short8*)&Blds[4096 + bfaddr[ni]];
            #pragma unroll
            for (int mi = 0; mi < 4; ++mi)
                #pragma unroll
                for (int ni = 0; ni < 4; ++ni)
                    acc[mi][ni] = __builtin_amdgcn_mfma_f32_16x16x32_bf16(
                        afB[mi], bf[ni], acc[mi][ni], 0, 0, 0);
        }

        abs_ += cs4;
    }
    #undef LOAD_A

    // ---- epilogue: C/D layout col=lane&15, row=quad*4+r ----
    #pragma unroll
    for (int ni = 0; ni < 4; ++ni) {
        const int ngl = nt * BN + wn + ni * 16 + lr;
        const float bv = bias[ngl];
        float* ybase = y + (((long)(batch * 512 + ngl)) << 10) + s0;
        #pragma unroll
        for (int mi = 0; mi < 4; ++mi) {
            const int mbase = wm + mi * 16 + quad * 4;
            #pragma unroll
            for (int r = 0; r < 4; ++r)
                ybase[mbase + r] = acc[mi][ni][r] + bv;
        }
    }
}

// ---------------- legacy fallback (round-1 kernel, ws too small) ----------------
#define LDA 40
#define LDB 40
__global__ __launch_bounds__(256) void convpbc_mfma(
    const float* __restrict__ x, const float* __restrict__ W,
    const float* __restrict__ bias, float* __restrict__ y)
{
    __shared__ __attribute__((aligned(16))) unsigned short Alds[BM * LDA];
    __shared__ __attribute__((aligned(16))) unsigned short BldsL[BN * LDB];
    const int tid = threadIdx.x, bid = blockIdx.x;
    const int nt = bid & 3, mt = bid >> 2, batch = mt >> 3;
    const int s0 = (mt & 7) * BM;
    const int lane = tid & 63, w = tid >> 6;
    const int wm = (w >> 1) * 64, wn = (w & 1) * 64;
    const int lr = lane & 15, quad = lane >> 4;
    const int sm = tid >> 1, half = tid & 1;
    const int s = s0 + sm, i0 = s >> 5, j0 = s & 31;
    const float* wrow = W + (long)(nt * BN + sm) * 4096;
    f32x4 acc[4][4] = {};
    for (int k0 = 0; k0 < 4096; k0 += 32) {
        {
            const int c = (k0 >> 4) + half;
            const float* xp = x + (((long)(batch * 256 + c)) << 10);
            __attribute__((aligned(16))) unsigned short tmp[16];
            #pragma unroll
            for (int t = 0; t < 16; ++t) {
                const int p = i0 + (t >> 2), q = j0 + (t & 3);
                const int v = p * 35 + q;
                const bool corner = (p >= 32) & (q >= 32);
                const bool valid = corner | (v < 1024);
                int idx = corner ? (((p - 32) << 5) + (q - 32)) : v;
                idx = valid ? idx : 0;
                float fv = xp[idx];
                fv = valid ? fv : 0.0f;
                tmp[t] = f2bf(fv);
            }
            short8* dst = (short8*)&Alds[sm * LDA + half * 16];
            dst[0] = *(const short8*)&tmp[0];
            dst[1] = *(const short8*)&tmp[8];
        }
        {
            const float4* wv = (const float4*)(wrow + k0 + half * 16);
            __attribute__((aligned(16))) unsigned short tmp[16];
            #pragma unroll
            for (int t4 = 0; t4 < 4; ++t4) {
                const float4 f = wv[t4];
                tmp[t4 * 4 + 0] = f2bf(f.x); tmp[t4 * 4 + 1] = f2bf(f.y);
                tmp[t4 * 4 + 2] = f2bf(f.z); tmp[t4 * 4 + 3] = f2bf(f.w);
            }
            short8* dst = (short8*)&BldsL[sm * LDB + half * 16];
            dst[0] = *(const short8*)&tmp[0];
            dst[1] = *(const short8*)&tmp[8];
        }
        __syncthreads();
        short8 af[4], bf[4];
        #pragma unroll
        for (int mi = 0; mi < 4; ++mi)
            af[mi] = *(const short8*)&Alds[(wm + mi * 16 + lr) * LDA + quad * 8];
        #pragma unroll
        for (int ni = 0; ni < 4; ++ni)
            bf[ni] = *(const short8*)&BldsL[(wn + ni * 16 + lr) * LDB + quad * 8];
        #pragma unroll
        for (int mi = 0; mi < 4; ++mi)
            #pragma unroll
            for (int ni = 0; ni < 4; ++ni)
                acc[mi][ni] = __builtin_amdgcn_mfma_f32_16x16x32_bf16(
                    af[mi], bf[ni], acc[mi][ni], 0, 0, 0);
        __syncthreads();
    }
    #pragma unroll
    for (int ni = 0; ni < 4; ++ni) {
        const int ngl = nt * BN + wn + ni * 16 + lr;
        const float bv = bias[ngl];
        float* ybase = y + (((long)(batch * 512 + ngl)) << 10) + s0;
        #pragma unroll
        for (int mi = 0; mi < 4; ++mi) {
            const int mbase = wm + mi * 16 + quad * 4;
            #pragma unroll
            for (int r = 0; r < 4; ++r)
                ybase[mbase + r] = acc[mi][ni][r] + bv;
        }
    }
}

extern "C" void kernel_launch(void* const* d_in, const int* in_sizes, int n_in,
                              void* d_out, int out_size, void* d_ws, size_t ws_size,
                              hipStream_t stream) {
    const float* x    = (const float*)d_in[0];
    const float* W    = (const float*)d_in[1];
    const float* bias = (const float*)d_in[2];
    float* y          = (float*)d_out;

    const size_t W_ELEMS = 512L * 4096;                       // 2,097,152
    const size_t XPAD_P  = 128L * 256 * 1232;                 // padded stride
    const size_t XPAD_S  = 128L * 256 * 1225;                 // tight stride
    const size_t NEED_P  = (XPAD_P + W_ELEMS) * 2;            // ~84.9 MB
    const size_t NEED_S  = (XPAD_S + W_ELEMS) * 2;            // ~84.5 MB

    if (ws_size >= NEED_P) {
        unsigned short* xpad = (unsigned short*)d_ws;
        unsigned short* Wb   = xpad + XPAD_P;
        hipLaunchKernelGGL(build_pad_vec, dim3(128 * 256), dim3(256), 0, stream, x, xpad);
        hipLaunchKernelGGL(cvt_w, dim3(1024), dim3(256), 0, stream, W, Wb);
        hipLaunchKernelGGL(convpbc_mfma3, dim3(4096), dim3(256), 0, stream,
                           xpad, Wb, bias, y, 1232);
    } else if (ws_size >= NEED_S) {
        unsigned short* xpad = (unsigned short*)d_ws;
        unsigned short* Wb   = xpad + XPAD_S;
        hipLaunchKernelGGL(build_pad_s, dim3(5, 128 * 256), dim3(256), 0, stream, x, xpad);
        hipLaunchKernelGGL(cvt_w, dim3(1024), dim3(256), 0, stream, W, Wb);
        hipLaunchKernelGGL(convpbc_mfma3, dim3(4096), dim3(256), 0, stream,
                           xpad, Wb, bias, y, 1225);
    } else {
        hipLaunchKernelGGL(convpbc_mfma, dim3(4096), dim3(256), 0, stream, x, W, bias, y);
    }
}